// Round 4
// baseline (147.758 us; speedup 1.0000x reference)
//
#include <hip/hip_runtime.h>
#include <math.h>

#define NH 64
#define NW 64
#define NB 4
#define CHI 256
#define CHO 256
#define XT_B (66 * 66 * 256)   // per-batch xT elements (zero-padded 66x66, ch-inner)

typedef __attribute__((ext_vector_type(8))) short bf16x8;   // MFMA A/B frag (4 VGPR)
typedef __attribute__((ext_vector_type(4))) float f32x4;    // MFMA C/D frag

static __device__ __forceinline__ unsigned short f2bf(float f) {
    unsigned int u = __float_as_uint(f);
    u += 0x7fffu + ((u >> 16) & 1u);     // RNE
    return (unsigned short)(u >> 16);
}
static __device__ __forceinline__ float bflo(unsigned int p) { return __uint_as_float(p << 16); }
static __device__ __forceinline__ float bfhi(unsigned int p) { return __uint_as_float(p & 0xffff0000u); }
// HW packed f32->bf16 RNE convert
static __device__ __forceinline__ unsigned int pkbf(float a, float b) {
    unsigned int r;
    asm("v_cvt_pk_bf16_f32 %0, %1, %2" : "=v"(r) : "v"(a), "v"(b));
    return r;
}

// lgkm-only barrier: ds ops drained, in-flight global gathers ride across.
#define BAR_LGKM() asm volatile("s_waitcnt lgkmcnt(0)\n\ts_barrier" ::: "memory")

// ws layout:
//   wB   bf16 [72][256 o][32 kin]   ks = cc*9+kt, kin = channel within 32-chunk cc
//   wOB  bf16 [72][32 oc][32 kin]
//   xT   bf16 [B][66 yp][66 xp][256 c]  zero halo at yp/xp = 0,65

// grid: [0,2304) wB pack | [2304,2592) wOB pack | [2592,3104) transpose | [3104,3624) halo zero
__global__ __launch_bounds__(256) void prep_all(const float* __restrict__ weight,
                                                const float* __restrict__ w_off,
                                                const float* __restrict__ x,
                                                unsigned short* __restrict__ wB,
                                                unsigned short* __restrict__ wOB,
                                                unsigned short* __restrict__ xT) {
    __shared__ unsigned short sT[64 * 134];
    int bid = blockIdx.x, tid = threadIdx.x;
    if (bid < 2304) {
        int idx = bid * 256 + tid;             // < 589824
        int kin = idx & 31, o = (idx >> 5) & 255, ks = idx >> 13;
        int cc = ks / 9, kt = ks - cc * 9;
        int c = cc * 32 + kin;
        wB[idx] = f2bf(weight[((size_t)o * CHI + c) * 9 + kt]);
    } else if (bid < 2592) {
        int idx = (bid - 2304) * 256 + tid;    // < 73728
        int kin = idx & 31, oc = (idx >> 5) & 31, ks = idx >> 10;
        int cc = ks / 9, kt = ks - cc * 9;
        int c = cc * 32 + kin;
        wOB[idx] = (oc < 27) ? f2bf(w_off[((size_t)oc * CHI + c) * 9 + kt])
                             : (unsigned short)0;
    } else if (bid < 3104) {
        int bid2 = bid - 2592;                 // 0..511
        int b = bid2 >> 7, rem = bid2 & 127;
        int y = rem >> 1, chalf = rem & 1;
        int c0 = chalf * 128;
        for (int rep = 0; rep < 8; ++rep) {
            int idx = rep * 256 + tid;         // 0..2047
            int c = idx >> 4, p4 = (idx & 15) * 4;
            const float* src = x + (((size_t)b * CHI + c0 + c) * 64 + y) * 64 + p4;
            float4 v = *(const float4*)src;
            sT[(p4 + 0) * 134 + c] = f2bf(v.x);
            sT[(p4 + 1) * 134 + c] = f2bf(v.y);
            sT[(p4 + 2) * 134 + c] = f2bf(v.z);
            sT[(p4 + 3) * 134 + c] = f2bf(v.w);
        }
        __syncthreads();
        unsigned int* dst = (unsigned int*)(xT + ((size_t)(b * 66 + y + 1) * 66 + 1) * 256)
                          + chalf * 64;
        for (int rep = 0; rep < 16; ++rep) {
            int idx = rep * 256 + tid;         // 0..4095
            int px = idx >> 6, cu = idx & 63;
            unsigned int lo = sT[px * 134 + cu * 2];
            unsigned int hi = sT[px * 134 + cu * 2 + 1];
            dst[(size_t)px * 128 + cu] = lo | (hi << 16);
        }
    } else {
        int flat = (bid - 3104) * 256 + tid;   // 0..133119 uints
        int b = flat / 33280, r = flat - b * 33280;
        unsigned int* xtu = (unsigned int*)xT;
        size_t base = (size_t)b * 66 * 66 * 128;
        size_t idx;
        if (r < 8448) {
            idx = base + r;
        } else if (r < 16896) {
            idx = base + (size_t)65 * 66 * 128 + (r - 8448);
        } else {
            int rc = r - 16896;
            int side = rc >> 13;
            int row = 1 + ((rc & 8191) >> 7);
            int cu = rc & 127;
            idx = base + ((size_t)row * 66 + (side ? 65 : 0)) * 128 + cu;
        }
        xtu[idx] = 0;
    }
}

// ---- fused: offset GEMM prologue + deformable sampling + MFMA GEMM + BN + ReLU ----
// 256 blocks (1/CU) x 1024 threads (16 waves). Block = one (b,h) row: M=64, N=256.
// vs r3: same wB traffic (1 block/CU reads wB once) but 2x waves for latency hiding.
// Consumer roles nb(4) x kq(4 K-quarters of 18 slices); 1 slice/wave/g (16 MFMA).
// Producers: slq(4 slice slots) x pxl(64) x cg8(4). __launch_bounds__(1024,4) is
// REQUIRED: 16-wave block needs 4 waves/SIMD -> VGPR <= 128 or it cannot launch.
__global__ __launch_bounds__(1024, 4) void dcn_fused(
        const unsigned short* __restrict__ xT,
        const unsigned short* __restrict__ wOB,
        const unsigned short* __restrict__ wB,
        const float* __restrict__ b_off,
        const float* __restrict__ bias, const float* __restrict__ gamma,
        const float* __restrict__ beta, const float* __restrict__ rmean,
        const float* __restrict__ rvar, float* __restrict__ out) {
    // LDS map: s_po [0,9216) s_cw [9216,18432) fixed.
    //   sA [18432,38912): 8 slots (2 phases x 4 quarters) x 64px x 40B
    //   sOff aliases [18432,52224): [4][64][33] f32 prologue partials
    //   sOut aliases [0,65536): [256 oc][16 float4] XOR-swizzled epilogue combine
    __shared__ __align__(16) unsigned char smem[66560];
    int4*   s_po = (int4*)smem;                                 // [576]
    float4* s_cw = (float4*)(smem + 9216);                      // [576]
    unsigned short* sA = (unsigned short*)(smem + 18432);
    float* sOff = (float*)(smem + 18432);
    float4* sOut = (float4*)smem;                               // swizzled [256][16]

// float4-slot index for epilogue combine: row oc (256), col p4>>2 (16 slots).
// XOR with oc&15 spreads the 16 ln-lanes across all 8 bank-quads (2-way = free).
#define SWZ(oc_, p4_) (((oc_) << 4) + ((((p4_) >> 2)) ^ ((oc_) & 15)))

    int id = blockIdx.x;                        // 256 blocks
    int xcd = id & 7, sl = id >> 3;             // 32 blocks per XCD
    int b = xcd >> 1;                           // batch pinned to XCD pair (xT L2 reuse)
    int h = (xcd & 1) * 32 + sl;                // output row

    int tid = threadIdx.x;
    int lane = tid & 63, q = tid >> 6;          // q = wave 0..15
    int ln = lane & 15, lk = lane >> 4;
    int nb = q & 3, kq = q >> 2;                // consumer: oc 64-group, K-quarter

    const unsigned short* xTfull = xT + (size_t)b * XT_B;
    const bf16x8* wOBv = (const bf16x8*)wOB;
    const bf16x8* wBv  = (const bf16x8*)wB;

    // ---- offset-conv prologue: om = xT . wOB (M=64, N=32, K=2304), 16 waves ----
    // roles: omt = px half, ont = oc 16-half, okq = K-quarter (2 cc each)
    {
        int omt = q & 1, ont = (q >> 1) & 1, okq = q >> 2;
        int px0 = omt * 32 + ln;
        int posb = (h + 1) * 66 + 1 + px0;
        f32x4 oa0 = {0.f,0.f,0.f,0.f}, oa1 = {0.f,0.f,0.f,0.f};
        for (int cc = okq * 2; cc < okq * 2 + 2; ++cc) {
#pragma unroll
            for (int kt = 0; kt < 9; ++kt) {
                int pos = posb + (kt / 3 - 1) * 66 + (kt % 3 - 1);
                bf16x8 A0 = *(const bf16x8*)&xTfull[(size_t)pos * 256 + cc * 32 + lk * 8];
                bf16x8 A1 = *(const bf16x8*)&xTfull[(size_t)(pos + 16) * 256 + cc * 32 + lk * 8];
                bf16x8 B0 = wOBv[((size_t)(cc * 9 + kt) * 32 + ont * 16 + ln) * 4 + lk];
                oa0 = __builtin_amdgcn_mfma_f32_16x16x32_bf16(A0, B0, oa0, 0, 0, 0);
                oa1 = __builtin_amdgcn_mfma_f32_16x16x32_bf16(A1, B0, oa1, 0, 0, 0);
            }
        }
#pragma unroll
        for (int r = 0; r < 4; ++r) {
            int row0 = omt * 32 + lk * 4 + r;
            sOff[(okq * 64 + row0) * 33 + ont * 16 + ln]      = oa0[r];
            sOff[(okq * 64 + row0 + 16) * 33 + ont * 16 + ln] = oa1[r];
        }
    }
    BAR_LGKM();

    // ---- bilinear metadata from the 4 K-quarter partials ----
    for (int p = tid; p < 576; p += 1024) {
        int k = p >> 6, pwl = p & 63;
        float dy = b_off[k], dx = b_off[k + 9], mp = b_off[k + 18];
#pragma unroll
        for (int jq = 0; jq < 4; ++jq) {
            dy += sOff[(jq * 64 + pwl) * 33 + k];
            dx += sOff[(jq * 64 + pwl) * 33 + k + 9];
            mp += sOff[(jq * 64 + pwl) * 33 + k + 18];
        }
        float mv = 1.f / (1.f + __expf(-mp));
        float py  = (float)h   + (float)(k / 3 - 1) + dy;
        float pxf = (float)pwl + (float)(k % 3 - 1) + dx;
        float y0f = floorf(py), x0f = floorf(pxf);
        int y0 = (int)y0f, x0 = (int)x0f;
        float ly = py - y0f, lx = pxf - x0f;
        int y0c = min(max(y0, -1), 64), y1c = min(max(y0 + 1, -1), 64);
        int x0c = min(max(x0, -1), 64), x1c = min(max(x0 + 1, -1), 64);
        int ry0 = (y0c + 1) * 66, ry1 = (y1c + 1) * 66;
        s_po[p] = make_int4(ry0 + x0c + 1, ry0 + x1c + 1, ry1 + x0c + 1, ry1 + x1c + 1);
        s_cw[p] = make_float4((1.f - ly) * (1.f - lx) * mv, (1.f - ly) * lx * mv,
                              ly * (1.f - lx) * mv,         ly * lx * mv);
    }

    // producer role: cg8 low bits (64B record coalescing), pxl 0..63, slq slice-slot
    int cg8 = tid & 3, pxl = (tid >> 2) & 63, slq = tid >> 8;   // slq 0..3
    const unsigned short* xTb = xTfull + cg8 * 8;

    f32x4 zf = {0.f, 0.f, 0.f, 0.f};
    f32x4 acc[4][4] = {{zf,zf,zf,zf},{zf,zf,zf,zf},{zf,zf,zf,zf},{zf,zf,zf,zf}};

    uint4 R0, R1, R2, R3;      // one gather set in flight

#define LOADSET(s) do { int s_ = (s);                                          \
        int cc_ = s_ / 9; int kt_ = s_ - cc_ * 9;                              \
        int4 o4_ = s_po[kt_ * 64 + pxl];                                       \
        const unsigned short* cb_ = xTb + cc_ * 32;                            \
        R0 = *(const uint4*)(cb_ + (size_t)o4_.x * 256);                       \
        R1 = *(const uint4*)(cb_ + (size_t)o4_.y * 256);                       \
        R2 = *(const uint4*)(cb_ + (size_t)o4_.z * 256);                       \
        R3 = *(const uint4*)(cb_ + (size_t)o4_.w * 256);                       \
    } while (0)

#define WRITESET(s, buf) do { int s_ = (s);                                    \
        int kt_ = s_ - (s_ / 9) * 9;                                           \
        float4 w_ = s_cw[kt_ * 64 + pxl];                                      \
        uint4 pk_;                                                             \
        pk_.x = pkbf(w_.x*bflo(R0.x)+w_.y*bflo(R1.x)+w_.z*bflo(R2.x)+w_.w*bflo(R3.x), \
                     w_.x*bfhi(R0.x)+w_.y*bfhi(R1.x)+w_.z*bfhi(R2.x)+w_.w*bfhi(R3.x)); \
        pk_.y = pkbf(w_.x*bflo(R0.y)+w_.y*bflo(R1.y)+w_.z*bflo(R2.y)+w_.w*bflo(R3.y), \
                     w_.x*bfhi(R0.y)+w_.y*bfhi(R1.y)+w_.z*bfhi(R2.y)+w_.w*bfhi(R3.y)); \
        pk_.z = pkbf(w_.x*bflo(R0.z)+w_.y*bflo(R1.z)+w_.z*bflo(R2.z)+w_.w*bflo(R3.z), \
                     w_.x*bfhi(R0.z)+w_.y*bfhi(R1.z)+w_.z*bfhi(R2.z)+w_.w*bfhi(R3.z)); \
        pk_.w = pkbf(w_.x*bflo(R0.w)+w_.y*bflo(R1.w)+w_.z*bflo(R2.w)+w_.w*bflo(R3.w), \
                     w_.x*bfhi(R0.w)+w_.y*bfhi(R1.w)+w_.z*bfhi(R2.w)+w_.w*bfhi(R3.w)); \
        *(uint4*)&sA[(buf) * 2560 + pxl * 40 + cg8 * 8] = pk_;                 \
    } while (0)

    BAR_LGKM();   // metadata ready; sOff region may now be overwritten by sA

    // pipeline prologue: write slice 0 of this slot into phase 0; prefetch slice 1
    LOADSET(slq * 18 + 0);
    WRITESET(slq * 18 + 0, slq);
    LOADSET(slq * 18 + 1);
    bf16x8 bfE[4];
#pragma unroll
    for (int j = 0; j < 4; ++j)
        bfE[j] = wBv[((size_t)(kq * 18) * 256 + nb * 64 + j * 16 + ln) * 4 + lk];
    BAR_LGKM();

    for (int g = 0; g < 18; ++g) {
        if (g + 1 < 18) WRITESET(slq * 18 + g + 1, ((g + 1) & 1) * 4 + slq);
        if (g + 2 < 18) LOADSET(slq * 18 + g + 2);

        const unsigned short* pA = &sA[((g & 1) * 4 + kq) * 2560];
        bf16x8 a0 = *(const bf16x8*)&pA[(0 * 16 + ln) * 40 + lk * 8];
        bf16x8 a1 = *(const bf16x8*)&pA[(1 * 16 + ln) * 40 + lk * 8];
        bf16x8 a2 = *(const bf16x8*)&pA[(2 * 16 + ln) * 40 + lk * 8];
        bf16x8 a3 = *(const bf16x8*)&pA[(3 * 16 + ln) * 40 + lk * 8];

#pragma unroll
        for (int j = 0; j < 4; ++j) {
            acc[0][j] = __builtin_amdgcn_mfma_f32_16x16x32_bf16(a0, bfE[j], acc[0][j], 0, 0, 0);
            acc[1][j] = __builtin_amdgcn_mfma_f32_16x16x32_bf16(a1, bfE[j], acc[1][j], 0, 0, 0);
            acc[2][j] = __builtin_amdgcn_mfma_f32_16x16x32_bf16(a2, bfE[j], acc[2][j], 0, 0, 0);
            acc[3][j] = __builtin_amdgcn_mfma_f32_16x16x32_bf16(a3, bfE[j], acc[3][j], 0, 0, 0);
        }
        if (g + 1 < 18) {   // refill after last use; ~1 g of slack before next consume
#pragma unroll
            for (int j = 0; j < 4; ++j)
                bfE[j] = wBv[((size_t)(kq * 18 + g + 1) * 256 + nb * 64 + j * 16 + ln) * 4 + lk];
        }
        BAR_LGKM();
    }
#undef LOADSET
#undef WRITESET

    // ---- 4-way K-quarter combine + BN + ReLU (swizzled f32x4 LDS buffer) ----
    if (kq == 3) {
#pragma unroll
        for (int m = 0; m < 4; ++m)
#pragma unroll
            for (int j = 0; j < 4; ++j) {
                int oc = nb * 64 + j * 16 + ln;
                sOut[SWZ(oc, m * 16 + lk * 4)] = *(float4*)&acc[m][j];
            }
    }
    __syncthreads();
    if (kq == 2) {
#pragma unroll
        for (int m = 0; m < 4; ++m)
#pragma unroll
            for (int j = 0; j < 4; ++j) {
                int oc = nb * 64 + j * 16 + ln;
                float4 v = sOut[SWZ(oc, m * 16 + lk * 4)];
                v.x += acc[m][j][0]; v.y += acc[m][j][1];
                v.z += acc[m][j][2]; v.w += acc[m][j][3];
                sOut[SWZ(oc, m * 16 + lk * 4)] = v;
            }
    }
    __syncthreads();
    if (kq == 1) {
#pragma unroll
        for (int m = 0; m < 4; ++m)
#pragma unroll
            for (int j = 0; j < 4; ++j) {
                int oc = nb * 64 + j * 16 + ln;
                float4 v = sOut[SWZ(oc, m * 16 + lk * 4)];
                v.x += acc[m][j][0]; v.y += acc[m][j][1];
                v.z += acc[m][j][2]; v.w += acc[m][j][3];
                sOut[SWZ(oc, m * 16 + lk * 4)] = v;
            }
    }
    __syncthreads();
    if (kq == 0) {
#pragma unroll
        for (int j = 0; j < 4; ++j) {
            int oc = nb * 64 + j * 16 + ln;
            float inv = gamma[oc] * rsqrtf(rvar[oc] + 1e-5f);
            float sh  = beta[oc] - rmean[oc] * inv + bias[oc] * inv;
#pragma unroll
            for (int m = 0; m < 4; ++m) {
                int row = m * 16 + lk * 4;
                float4 v = sOut[SWZ(oc, row)];
                float4 rr;
                rr.x = fmaxf((acc[m][j][0] + v.x) * inv + sh, 0.f);
                rr.y = fmaxf((acc[m][j][1] + v.y) * inv + sh, 0.f);
                rr.z = fmaxf((acc[m][j][2] + v.z) * inv + sh, 0.f);
                rr.w = fmaxf((acc[m][j][3] + v.w) * inv + sh, 0.f);
                size_t oi = (((size_t)b * 256 + oc) * 64 + h) * 64 + row;
                *(float4*)(out + oi) = rr;
            }
        }
    }
#undef SWZ
}

extern "C" void kernel_launch(void* const* d_in, const int* in_sizes, int n_in,
                              void* d_out, int out_size, void* d_ws, size_t ws_size,
                              hipStream_t stream) {
    const float* x      = (const float*)d_in[0];
    const float* w_off  = (const float*)d_in[1];
    const float* b_off  = (const float*)d_in[2];
    const float* weight = (const float*)d_in[3];
    const float* bias   = (const float*)d_in[4];
    const float* gamma  = (const float*)d_in[5];
    const float* beta   = (const float*)d_in[6];
    const float* rmean  = (const float*)d_in[7];
    const float* rvar   = (const float*)d_in[8];
    float* out = (float*)d_out;

    unsigned short* wB  = (unsigned short*)d_ws;             // 589824 bf16
    unsigned short* wOB = wB + 589824;                       // 73728 bf16
    unsigned short* xT  = wOB + 73728;                       // 4 * 66*66*256 bf16

    hipLaunchKernelGGL(prep_all, dim3(3624), dim3(256), 0, stream,
                       weight, w_off, x, wB, wOB, xT);
    hipLaunchKernelGGL(dcn_fused, dim3(256), dim3(1024), 0, stream,
                       xT, wOB, wB, b_off, bias, gamma, beta, rmean, rvar, out);
}